// Round 3
// baseline (822.829 us; speedup 1.0000x reference)
//
#include <hip/hip_runtime.h>

// MPNN: N=50000, E=800000, DIN=64, EIN=32, EOUT=64, H=128, DOUT=64
// R3:
//  - edge_kernel: weights held in REGISTERS (112 VGPR/wave slice), 8 tiles per block ->
//    weight L2 traffic /8; separate eins/hsm/outs LDS buffers (71.7KB, 2 blocks/CU)
//    cut barriers to 3/tile and let stores overlap next gather.
//  - linked-list agg replaced by CSR (deg -> block scan -> atomic fill): agg loads become
//    independent (4-way unrolled), killing the serial e=nxt[e] dependent-load chain.

typedef unsigned short u16;
typedef __attribute__((ext_vector_type(8))) short bf16x8;
typedef __attribute__((ext_vector_type(4))) float f32x4;

#define NN 50000
#define NE 800000

__device__ __forceinline__ u16 f2bf(float f){
  union { float f; unsigned int i; } v; v.f = f;
  unsigned int i = v.i;
  return (u16)((i + 0x7FFFu + ((i >> 16) & 1u)) >> 16);  // RNE
}
__device__ __forceinline__ uint2 f4tobf(float4 f){
  uint2 p;
  p.x = (unsigned)f2bf(f.x) | ((unsigned)f2bf(f.y) << 16);
  p.y = (unsigned)f2bf(f.z) | ((unsigned)f2bf(f.w) << 16);
  return p;
}

// ---------------- prep: f32 weights -> transposed bf16 [n][k]; deg = 0 ----------------
__global__ void prep_kernel(const float* __restrict__ We1, const float* __restrict__ Wa1,
                            const float* __restrict__ We2, const float* __restrict__ Wa2,
                            const float* __restrict__ Wn1, const float* __restrict__ Wn2,
                            u16* __restrict__ w1t, u16* __restrict__ w2t,
                            u16* __restrict__ wn1t, u16* __restrict__ wn2t,
                            int* __restrict__ deg)
{
  int i = blockIdx.x * 256 + threadIdx.x;
  if (i < 40960) {
    int n = i / 160, k = i % 160;
    w1t[i] = f2bf((n < 128) ? We1[k*128 + n] : Wa1[k*128 + (n-128)]);
  } else if (i < 51200) {
    int j = i - 40960; int n = j / 128, k = j % 128;
    float v = (n < 64) ? We2[k*64 + n] : ((n == 64) ? Wa2[k] : 0.f);
    w2t[j] = f2bf(v);
  } else if (i < 67584) {
    int j = i - 51200; int n = j / 128, k = j % 128;
    wn1t[j] = f2bf(Wn1[k*128 + n]);
  } else if (i < 75776) {
    int j = i - 67584; int n = j / 128, k = j % 128;
    wn2t[j] = f2bf(Wn2[k*64 + n]);
  } else if (i < 125776) {
    deg[i - 75776] = 0;
  }
}

// ---------------- nf f32->bf16 + degree count (NE == NN*16 work items) ----------------
__global__ void deg_nfbf_kernel(const float* __restrict__ nf, u16* __restrict__ nfb,
                                const int* __restrict__ dst, int* __restrict__ deg)
{
  int i = blockIdx.x * 256 + threadIdx.x;
  if (i >= NE) return;               // NE == NN*16 exactly
  float4 f = *(const float4*)(nf + (size_t)i * 4);
  *(uint2*)&nfb[(size_t)i * 4] = f4tobf(f);
  atomicAdd(&deg[dst[i]], 1);
}

// ---------------- CSR build: block scan (196 blocks x 256 covers 50000) --------------
__global__ void scan1_kernel(const int* __restrict__ deg, int* __restrict__ part,
                             int* __restrict__ bsum)
{
  __shared__ int sm[256];
  int t = threadIdx.x, g = blockIdx.x * 256 + t;
  int x = (g < NN) ? deg[g] : 0;
  sm[t] = x; __syncthreads();
  #pragma unroll
  for (int o = 1; o < 256; o <<= 1) {
    int y = (t >= o) ? sm[t - o] : 0; __syncthreads();
    sm[t] += y; __syncthreads();
  }
  if (g < NN) part[g] = sm[t] - x;          // exclusive within block
  if (t == 255) bsum[blockIdx.x] = sm[255];
}

__global__ void scan2_kernel(int* __restrict__ bsum)
{
  __shared__ int sm[256];
  int t = threadIdx.x;
  int x = (t < 196) ? bsum[t] : 0;
  sm[t] = x; __syncthreads();
  #pragma unroll
  for (int o = 1; o < 256; o <<= 1) {
    int y = (t >= o) ? sm[t - o] : 0; __syncthreads();
    sm[t] += y; __syncthreads();
  }
  if (t < 196) bsum[t] = sm[t] - x;         // exclusive, in place
}

__global__ void scan3_kernel(const int* __restrict__ part, const int* __restrict__ bsum,
                             int* __restrict__ rowptr, int* __restrict__ cursor)
{
  int g = blockIdx.x * 256 + threadIdx.x;
  if (g >= NN) return;
  int r = part[g] + bsum[blockIdx.x];
  rowptr[g] = r; cursor[g] = r;
}

__global__ void fill_kernel(const int* __restrict__ dst, int* __restrict__ cursor,
                            int* __restrict__ csr_e)
{
  int e = blockIdx.x * 256 + threadIdx.x;
  if (e >= NE) return;
  int slot = atomicAdd(&cursor[dst[e]], 1);
  csr_e[slot] = e;
}
// after fill: cursor[v] == rowptr[v] + deg[v]  (= row end)

// ---------------- edge MLP + attn logit (MFMA, register weights, 8 tiles/block) -------
// Wave w owns L1 output cols [64w,64w+64) (20 frags) + L2 colfrag w (4) + logit (4):
// 28 bf16x8 = 112 VGPR, loaded ONCE per block. 3 barriers per 64-edge tile.
__global__ __launch_bounds__(256, 2) void edge_kernel(
    const u16* __restrict__ nfb, const float* __restrict__ ef,
    const int* __restrict__ src, const int* __restrict__ dst,
    const u16* __restrict__ w1t, const u16* __restrict__ w2t,
    const float* __restrict__ be1, const float* __restrict__ ba1,
    const float* __restrict__ be2, const float* __restrict__ ba2,
    float* __restrict__ uh_e, float* __restrict__ exu)
{
  __shared__ u16 eins[64*168];       // [64][160] pad->168 (21504 B)
  __shared__ u16 hsm [64*264];       // [64][256] pad->264 (33792 B)
  __shared__ float outs[64*64];      // (16384 B)  total 71680 B -> 2 blocks/CU

  const int t = threadIdx.x;
  const int lane = t & 63, wave = t >> 6;
  const int r = lane & 15, quad = lane >> 4;

  // ---- per-block: wave's weight slice -> registers ----
  bf16x8 wv1[5][4];                  // [k0][j]
  #pragma unroll
  for (int k = 0; k < 5; k++)
    #pragma unroll
    for (int j = 0; j < 4; j++)
      wv1[k][j] = *(const bf16x8*)(w1t + (size_t)((wave*4 + j)*16 + r)*160 + k*32 + quad*8);
  bf16x8 wv2[4], wvl[4];
  #pragma unroll
  for (int k = 0; k < 4; k++) {
    wv2[k] = *(const bf16x8*)(w2t + (size_t)(wave*16 + r)*128 + k*32 + quad*8);
    wvl[k] = *(const bf16x8*)(w2t + (size_t)(64 + r)*128 + k*32 + quad*8);
  }
  float bias1[4];
  #pragma unroll
  for (int j = 0; j < 4; j++) {
    int col = (wave*4 + j)*16 + r;
    bias1[j] = (col < 128) ? be1[col] : ba1[col - 128];
  }
  const float bias2 = be2[wave*16 + r];
  const float biasl = ba2[0];

  for (int tt0 = 0; tt0 < 8; tt0++) {
    int tile = blockIdx.x * 8 + tt0;
    if (tile >= NE/64) break;
    const int base = tile * 64;

    // gather (direct src/dst loads; 16 lanes share a row -> same cache line)
    #pragma unroll
    for (int i = 0; i < 4; i++) {
      int idx = i*256 + t;
      int e = idx >> 4, c = idx & 15;
      int sv = src[base + e];
      *(uint2*)&eins[e*168 + c*4] = *(const uint2*)(nfb + (size_t)sv*64 + c*4);
    }
    #pragma unroll
    for (int i = 0; i < 4; i++) {
      int idx = i*256 + t;
      int e = idx >> 4, c = idx & 15;
      int dv = dst[base + e];
      *(uint2*)&eins[e*168 + 64 + c*4] = *(const uint2*)(nfb + (size_t)dv*64 + c*4);
    }
    #pragma unroll
    for (int i = 0; i < 2; i++) {
      int idx = i*256 + t;
      int e = idx >> 3, c = idx & 7;
      float4 f = *(const float4*)(ef + (size_t)(base + e)*32 + c*4);
      *(uint2*)&eins[e*168 + 128 + c*4] = f4tobf(f);
    }
    __syncthreads();                 // bar1: eins ready (also: prev-tile outs reads done)

    // ---- layer 1 ----
    f32x4 acc[4][4];
    #pragma unroll
    for (int rf = 0; rf < 4; rf++)
      #pragma unroll
      for (int j = 0; j < 4; j++) acc[rf][j] = {0.f, 0.f, 0.f, 0.f};

    #pragma unroll
    for (int k = 0; k < 5; k++) {
      bf16x8 a[4];
      #pragma unroll
      for (int rf = 0; rf < 4; rf++)
        a[rf] = *(const bf16x8*)&eins[(rf*16 + r)*168 + k*32 + quad*8];
      #pragma unroll
      for (int j = 0; j < 4; j++)
        #pragma unroll
        for (int rf = 0; rf < 4; rf++)
          acc[rf][j] = __builtin_amdgcn_mfma_f32_16x16x32_bf16(a[rf], wv1[k][j], acc[rf][j], 0, 0, 0);
    }

    // bias + relu -> hsm (separate buffer, no hazard with eins)
    #pragma unroll
    for (int j = 0; j < 4; j++) {
      int col = (wave*4 + j)*16 + r;
      #pragma unroll
      for (int rf = 0; rf < 4; rf++)
        #pragma unroll
        for (int i = 0; i < 4; i++) {
          float h = fmaxf(acc[rf][j][i] + bias1[j], 0.f);
          hsm[(rf*16 + quad*4 + i)*264 + col] = f2bf(h);
        }
    }
    __syncthreads();                 // bar2: hsm ready

    // ---- layer 2 ----
    f32x4 acc2[4];
    f32x4 accl = {0.f, 0.f, 0.f, 0.f};
    #pragma unroll
    for (int rf = 0; rf < 4; rf++) acc2[rf] = {0.f, 0.f, 0.f, 0.f};
    #pragma unroll
    for (int k = 0; k < 4; k++) {
      #pragma unroll
      for (int rf = 0; rf < 4; rf++) {
        bf16x8 ae = *(const bf16x8*)&hsm[(rf*16 + r)*264 + k*32 + quad*8];
        acc2[rf] = __builtin_amdgcn_mfma_f32_16x16x32_bf16(ae, wv2[k], acc2[rf], 0, 0, 0);
      }
      bf16x8 al = *(const bf16x8*)&hsm[(wave*16 + r)*264 + 128 + k*32 + quad*8];
      accl = __builtin_amdgcn_mfma_f32_16x16x32_bf16(al, wvl[k], accl, 0, 0, 0);
    }

    // epilogue -> outs (separate buffer); exp(logit) -> global
    {
      int col = wave*16 + r;
      #pragma unroll
      for (int rf = 0; rf < 4; rf++)
        #pragma unroll
        for (int i = 0; i < 4; i++)
          outs[(rf*16 + quad*4 + i)*64 + col] = acc2[rf][i] + bias2;
    }
    if (r == 0) {
      #pragma unroll
      for (int i = 0; i < 4; i++) {
        int row = wave*16 + quad*4 + i;
        float x = __expf(fminf(fmaxf(accl[i] + biasl, -50.f), 50.f));
        exu[base + row] = x;
      }
    }
    __syncthreads();                 // bar3: outs ready (also: hsm reads done)

    // coalesced uh_e store (overlaps next tile's gather; no barrier needed after)
    #pragma unroll
    for (int i = 0; i < 4; i++) {
      int idx = i*256 + t;
      int row = idx >> 4, c = idx & 15;
      *(float4*)(uh_e + (size_t)(base + row)*64 + c*4) = *(const float4*)&outs[row*64 + c*4];
    }
  }
}

// ---------------- attention-weighted aggregation (wave per node, CSR, ILP-4) ----------
__global__ void agg_kernel(const int* __restrict__ rowptr, const int* __restrict__ rowend,
                           const int* __restrict__ csr_e, const float* __restrict__ exu,
                           const float* __restrict__ uh_e, float* __restrict__ aggf)
{
  int gid = blockIdx.x * 256 + threadIdx.x;
  int v = gid >> 6, lane = gid & 63;
  if (v >= NN) return;
  int beg = rowptr[v], end = rowend[v];
  float acc = 0.f, s = 0.f;
  int i = beg;
  for (; i + 4 <= end; i += 4) {
    int e0 = csr_e[i], e1 = csr_e[i+1], e2 = csr_e[i+2], e3 = csr_e[i+3];
    float x0 = exu[e0], x1 = exu[e1], x2 = exu[e2], x3 = exu[e3];
    float u0 = uh_e[(size_t)e0*64 + lane];
    float u1 = uh_e[(size_t)e1*64 + lane];
    float u2 = uh_e[(size_t)e2*64 + lane];
    float u3 = uh_e[(size_t)e3*64 + lane];
    s += x0 + x1 + x2 + x3;
    acc += x0*u0 + x1*u1 + x2*u2 + x3*u3;
  }
  for (; i < end; i++) {
    int e = csr_e[i];
    float x = exu[e];
    s += x;
    acc += x * uh_e[(size_t)e*64 + lane];
  }
  aggf[(size_t)v*64 + lane] = acc / fmaxf(s, 1e-38f);
}

// ---------------- node MLP (MFMA); reads agg from uh_n region, overwrites with uh_n ----
__global__ __launch_bounds__(256, 4) void node_kernel(
    const float* __restrict__ aggf, const float* __restrict__ nf,
    const u16* __restrict__ wn1t, const u16* __restrict__ wn2t,
    const float* __restrict__ bn1, const float* __restrict__ bn2,
    float* __restrict__ uh_n)
{
  __shared__ u16 smem[8704];         // 17408 B union
  u16* xs = smem;                    // [64][136]
  float* outs = (float*)smem;        // [64][64]

  const int t = threadIdx.x;
  const int base = blockIdx.x * 64;

  #pragma unroll
  for (int i = 0; i < 8; i++) {
    int idx = i*256 + t;
    int row = idx >> 5, c = idx & 31;
    int v = base + row;
    float4 f = {0.f, 0.f, 0.f, 0.f};
    if (v < NN) {
      if (c < 16) f = *(const float4*)(aggf + (size_t)v*64 + c*4);
      else        f = *(const float4*)(nf   + (size_t)v*64 + (c-16)*4);
    }
    *(uint2*)&xs[row*136 + c*4] = f4tobf(f);
  }
  __syncthreads();

  const int lane = t & 63, wave = t >> 6;
  const int r = lane & 15, quad = lane >> 4;

  f32x4 acc1[8];
  #pragma unroll
  for (int i = 0; i < 8; i++) acc1[i] = {0.f, 0.f, 0.f, 0.f};
  #pragma unroll
  for (int k0 = 0; k0 < 128; k0 += 32) {
    bf16x8 a = *(const bf16x8*)&xs[(wave*16 + r)*136 + k0 + quad*8];
    #pragma unroll
    for (int tt = 0; tt < 8; tt++) {
      bf16x8 b = *(const bf16x8*)(wn1t + (size_t)(tt*16 + r)*128 + k0 + quad*8);
      acc1[tt] = __builtin_amdgcn_mfma_f32_16x16x32_bf16(a, b, acc1[tt], 0, 0, 0);
    }
  }
  __syncthreads();

  u16* hb = smem + wave*(16*136);
  #pragma unroll
  for (int tt = 0; tt < 8; tt++) {
    int col = tt*16 + r;
    float bias = bn1[col];
    #pragma unroll
    for (int i = 0; i < 4; i++) {
      float h = fmaxf(acc1[tt][i] + bias, 0.f);
      hb[(quad*4 + i)*136 + col] = f2bf(h);
    }
  }
  __syncthreads();

  f32x4 acc2[4];
  #pragma unroll
  for (int i = 0; i < 4; i++) acc2[i] = {0.f, 0.f, 0.f, 0.f};
  #pragma unroll
  for (int k0 = 0; k0 < 128; k0 += 32) {
    bf16x8 a = *(const bf16x8*)&hb[r*136 + k0 + quad*8];
    #pragma unroll
    for (int tt = 0; tt < 4; tt++) {
      bf16x8 b = *(const bf16x8*)(wn2t + (size_t)(tt*16 + r)*128 + k0 + quad*8);
      acc2[tt] = __builtin_amdgcn_mfma_f32_16x16x32_bf16(a, b, acc2[tt], 0, 0, 0);
    }
  }
  __syncthreads();

  #pragma unroll
  for (int tt = 0; tt < 4; tt++) {
    int col = tt*16 + r;
    float bias = bn2[col];
    #pragma unroll
    for (int i = 0; i < 4; i++)
      outs[(wave*16 + quad*4 + i)*64 + col] = acc2[tt][i] + bias;
  }
  __syncthreads();

  #pragma unroll
  for (int i = 0; i < 4; i++) {
    int idx = i*256 + t;
    int row = idx >> 4, c = idx & 15;
    int v2 = base + row;
    if (v2 < NN)
      *(float4*)(uh_n + (size_t)v2*64 + c*4) = *(const float4*)&outs[row*64 + c*4];
  }
}

// ---------------- launch ----------------
extern "C" void kernel_launch(void* const* d_in, const int* in_sizes, int n_in,
                              void* d_out, int out_size, void* d_ws, size_t ws_size,
                              hipStream_t stream)
{
  const float* nf  = (const float*)d_in[0];
  const float* ef  = (const float*)d_in[1];
  const int*   src = (const int*)d_in[2];
  const int*   dst = (const int*)d_in[3];
  const float* We1 = (const float*)d_in[4];
  const float* be1 = (const float*)d_in[5];
  const float* We2 = (const float*)d_in[6];
  const float* be2 = (const float*)d_in[7];
  const float* Wa1 = (const float*)d_in[8];
  const float* ba1 = (const float*)d_in[9];
  const float* Wa2 = (const float*)d_in[10];
  const float* ba2 = (const float*)d_in[11];
  const float* Wn1 = (const float*)d_in[12];
  const float* bn1 = (const float*)d_in[13];
  const float* Wn2 = (const float*)d_in[14];
  const float* bn2 = (const float*)d_in[15];

  // workspace layout (bytes), total ~7.35 MB
  char* ws = (char*)d_ws;
  u16*   w1t    = (u16*)  (ws + 0);         //  81920
  u16*   w2t    = (u16*)  (ws + 81920);     //  20480
  u16*   wn1t   = (u16*)  (ws + 102400);    //  32768
  u16*   wn2t   = (u16*)  (ws + 135168);    //  16384
  float* exu    = (float*)(ws + 151552);    //  NE*4 = 3200000 -> 3351552
  int*   deg    = (int*)  (ws + 3351552);   //  NN*4 -> 3551552
  int*   part   = (int*)  (ws + 3551552);   //  NN*4 -> 3751552
  int*   rowptr = (int*)  (ws + 3751552);   //  NN*4 -> 3951552
  int*   cursor = (int*)  (ws + 3951552);   //  NN*4 -> 4151552
  int*   bsum   = (int*)  (ws + 4151552);   //  1024 -> 4152576
  int*   csr_e  = (int*)  (ws + 4152576);   //  NE*4 -> 7352576

  float* uh_n = (float*)d_out;                     // [NN, 64] f32
  float* uh_e = (float*)d_out + (size_t)NN * 64;   // [NE, 64] f32
  // nfb (bf16 nf, 6.4 MB) lives in uh_n region: consumed only by edge_kernel,
  // overwritten afterwards by agg_kernel's aggf output.
  u16*   nfb  = (u16*)d_out;
  float* aggf = uh_n;

  prep_kernel<<<492, 256, 0, stream>>>(We1, Wa1, We2, Wa2, Wn1, Wn2,
                                       w1t, w2t, wn1t, wn2t, deg);
  deg_nfbf_kernel<<<(NE + 255)/256, 256, 0, stream>>>(nf, nfb, dst, deg);
  scan1_kernel<<<196, 256, 0, stream>>>(deg, part, bsum);
  scan2_kernel<<<1, 256, 0, stream>>>(bsum);
  scan3_kernel<<<196, 256, 0, stream>>>(part, bsum, rowptr, cursor);
  fill_kernel<<<(NE + 255)/256, 256, 0, stream>>>(dst, cursor, csr_e);
  edge_kernel<<<(NE/64 + 7)/8, 256, 0, stream>>>(nfb, ef, src, dst, w1t, w2t,
                                                 be1, ba1, be2, ba2, uh_e, exu);
  agg_kernel<<<(NN*64)/256, 256, 0, stream>>>(rowptr, cursor, csr_e, exu, uh_e, aggf);
  node_kernel<<<(NN + 63)/64, 256, 0, stream>>>(aggf, nf, wn1t, wn2t, bn1, bn2, uh_n);
}

// Round 5
// 646.927 us; speedup vs baseline: 1.2719x; 1.2719x over previous
//
#include <hip/hip_runtime.h>

// MPNN: N=50000, E=800000, DIN=64, EIN=32, EOUT=64, H=128, DOUT=64
// R5: R4's 160KB dynamic-LDS launch likely failed silently (sharedMemPerBlock=64KB).
// Redo the same levers within 64KB STATIC LDS:
//  - weights in registers (R3's verified load code), amortized over 8 tiles/block;
//    __launch_bounds__(256,1) so the allocator keeps them hoisted (R3 failure: it
//    chose 128 VGPR under (256,2) and re-streamed weights every k-step)
//  - issue-early/write-late gather: tile t+1 global loads issued at top of tile t,
//    LDS-written after BAR3 (hsm dead) -> HBM latency hidden under full tile compute
//  - LDS: union(eins 21504 / hsm 33792) + outs 16384 = 50176 B static
//  - non-edge kernels: R2-exact (verified)

typedef unsigned short u16;
typedef __attribute__((ext_vector_type(8))) short bf16x8;
typedef __attribute__((ext_vector_type(4))) float f32x4;

#define NN 50000
#define NE 800000
#define NT 12500          // NE/64
#define TPB 8             // tiles per block
#define EGRID ((NT + TPB - 1) / TPB)   // 1563

__device__ __forceinline__ u16 f2bf(float f){
  union { float f; unsigned int i; } v; v.f = f;
  unsigned int i = v.i;
  return (u16)((i + 0x7FFFu + ((i >> 16) & 1u)) >> 16);  // RNE
}
__device__ __forceinline__ uint2 f4tobf(float4 f){
  uint2 p;
  p.x = (unsigned)f2bf(f.x) | ((unsigned)f2bf(f.y) << 16);
  p.y = (unsigned)f2bf(f.z) | ((unsigned)f2bf(f.w) << 16);
  return p;
}

// ---------------- prep: f32 weights -> transposed bf16 [n][k]; head = -1 ----------------
__global__ void prep_kernel(const float* __restrict__ We1, const float* __restrict__ Wa1,
                            const float* __restrict__ We2, const float* __restrict__ Wa2,
                            const float* __restrict__ Wn1, const float* __restrict__ Wn2,
                            u16* __restrict__ w1t, u16* __restrict__ w2t,
                            u16* __restrict__ wn1t, u16* __restrict__ wn2t,
                            int* __restrict__ head)
{
  int i = blockIdx.x * 256 + threadIdx.x;
  if (i < 40960) {
    int n = i / 160, k = i % 160;
    w1t[i] = f2bf((n < 128) ? We1[k*128 + n] : Wa1[k*128 + (n-128)]);
  } else if (i < 51200) {
    int j = i - 40960; int n = j / 128, k = j % 128;
    float v = (n < 64) ? We2[k*64 + n] : ((n == 64) ? Wa2[k] : 0.f);
    w2t[j] = f2bf(v);
  } else if (i < 67584) {
    int j = i - 51200; int n = j / 128, k = j % 128;
    wn1t[j] = f2bf(Wn1[k*128 + n]);
  } else if (i < 75776) {
    int j = i - 67584; int n = j / 128, k = j % 128;
    wn2t[j] = f2bf(Wn2[k*64 + n]);
  } else if (i < 125776) {
    head[i - 75776] = -1;
  }
}

// ---------------- nf f32 -> bf16 (once) ----------------
__global__ void nfbf_kernel(const float* __restrict__ nf, u16* __restrict__ nfb)
{
  int i = blockIdx.x * 256 + threadIdx.x;   // NN*16 float4 chunks
  if (i >= NN * 16) return;
  float4 f = *(const float4*)(nf + (size_t)i * 4);
  *(uint2*)&nfb[(size_t)i * 4] = f4tobf(f);
}

// ---------------- linked-list build over dst ----------------
__global__ void link_kernel(const int* __restrict__ dst, int* __restrict__ head,
                            int* __restrict__ nxt)
{
  int e = blockIdx.x * 256 + threadIdx.x;
  if (e >= NE) return;
  nxt[e] = atomicExch(&head[dst[e]], e);
}

// ---------------- edge MLP + attn logit (register weights, pipelined gather) ----------
__global__ __launch_bounds__(256, 1) void edge_kernel(
    const u16* __restrict__ nfb, const float* __restrict__ ef,
    const int* __restrict__ src, const int* __restrict__ dst,
    const u16* __restrict__ w1t, const u16* __restrict__ w2t,
    const float* __restrict__ be1, const float* __restrict__ ba1,
    const float* __restrict__ be2, const float* __restrict__ ba2,
    float* __restrict__ uh_e, float* __restrict__ exu)
{
  __shared__ u16 smem[16896];        // 33792 B: eins[64][168] UNION hsm[64][264]
  __shared__ float outs[64*64];      // 16384 B separate
  u16* eins = smem;
  u16* hsm  = smem;

  const int t = threadIdx.x;
  const int lane = t & 63, wave = t >> 6;
  const int r = lane & 15, quad = lane >> 4;

  const int tile0 = blockIdx.x * TPB;
  const int ntiles = (NT - tile0 < TPB) ? (NT - tile0) : TPB;

  // ---- weights -> registers (once per block; 28 bf16x8 = 112 VGPR/wave) ----
  bf16x8 wv1[5][4];                  // [k0][j]
  #pragma unroll
  for (int k = 0; k < 5; k++)
    #pragma unroll
    for (int j = 0; j < 4; j++)
      wv1[k][j] = *(const bf16x8*)(w1t + (size_t)((wave*4 + j)*16 + r)*160 + k*32 + quad*8);
  bf16x8 wv2[4], wvl[4];
  #pragma unroll
  for (int k = 0; k < 4; k++) {
    wv2[k] = *(const bf16x8*)(w2t + (size_t)(wave*16 + r)*128 + k*32 + quad*8);
    wvl[k] = *(const bf16x8*)(w2t + (size_t)(64 + r)*128 + k*32 + quad*8);
  }
  float bias1[4];
  #pragma unroll
  for (int j = 0; j < 4; j++) {
    int col = (wave*4 + j)*16 + r;
    bias1[j] = (col < 128) ? be1[col] : ba1[col - 128];
  }
  const float bias2 = be2[wave*16 + r];
  const float biasl = ba2[0];

  // ---- prologue: gather tile0 -> regs -> eins ----
  uint2 gs[4], gd[4]; float4 gef[2];
  {
    const int nb = tile0 * 64;
    #pragma unroll
    for (int i = 0; i < 4; i++) {
      int idx = i*256 + t, e = idx >> 4, c = idx & 15;
      gs[i] = *(const uint2*)(nfb + (size_t)src[nb + e]*64 + c*4);
      gd[i] = *(const uint2*)(nfb + (size_t)dst[nb + e]*64 + c*4);
    }
    #pragma unroll
    for (int i = 0; i < 2; i++) {
      int idx = i*256 + t, e = idx >> 3, c = idx & 7;
      gef[i] = *(const float4*)(ef + (size_t)(nb + e)*32 + c*4);
    }
    #pragma unroll
    for (int i = 0; i < 4; i++) {
      int idx = i*256 + t, e = idx >> 4, c = idx & 15;
      *(uint2*)&eins[e*168 + c*4]      = gs[i];
      *(uint2*)&eins[e*168 + 64 + c*4] = gd[i];
    }
    #pragma unroll
    for (int i = 0; i < 2; i++) {
      int idx = i*256 + t, e = idx >> 3, c = idx & 7;
      *(uint2*)&eins[e*168 + 128 + c*4] = f4tobf(gef[i]);
    }
  }
  __syncthreads();                   // eins(tile0) ready

  // ---- main loop ----
  for (int tt = 0; tt < ntiles; tt++) {
    const int nbase = (tile0 + tt) * 64;

    // issue next-tile gather -> regs (latency spans this tile's compute)
    if (tt + 1 < ntiles) {
      const int nb = nbase + 64;
      #pragma unroll
      for (int i = 0; i < 4; i++) {
        int idx = i*256 + t, e = idx >> 4, c = idx & 15;
        gs[i] = *(const uint2*)(nfb + (size_t)src[nb + e]*64 + c*4);
        gd[i] = *(const uint2*)(nfb + (size_t)dst[nb + e]*64 + c*4);
      }
      #pragma unroll
      for (int i = 0; i < 2; i++) {
        int idx = i*256 + t, e = idx >> 3, c = idx & 7;
        gef[i] = *(const float4*)(ef + (size_t)(nb + e)*32 + c*4);
      }
    }

    // ---- layer 1: eins[64x160] @ W1[160x256], wave w -> colfrags 4w..4w+3 ----
    f32x4 acc[4][4];
    #pragma unroll
    for (int rf = 0; rf < 4; rf++)
      #pragma unroll
      for (int j = 0; j < 4; j++) acc[rf][j] = {0.f, 0.f, 0.f, 0.f};

    #pragma unroll
    for (int k = 0; k < 5; k++) {
      bf16x8 a[4];
      #pragma unroll
      for (int rf = 0; rf < 4; rf++)
        a[rf] = *(const bf16x8*)&eins[(rf*16 + r)*168 + k*32 + quad*8];
      #pragma unroll
      for (int j = 0; j < 4; j++)
        #pragma unroll
        for (int rf = 0; rf < 4; rf++)
          acc[rf][j] = __builtin_amdgcn_mfma_f32_16x16x32_bf16(a[rf], wv1[k][j], acc[rf][j], 0, 0, 0);
    }
    __syncthreads();                 // BAR1: eins reads done (eins dead)

    // bias + relu -> hsm (clobbers eins region; safe after BAR1)
    #pragma unroll
    for (int j = 0; j < 4; j++) {
      int col = (wave*4 + j)*16 + r;
      #pragma unroll
      for (int rf = 0; rf < 4; rf++)
        #pragma unroll
        for (int i = 0; i < 4; i++) {
          float h = fmaxf(acc[rf][j][i] + bias1[j], 0.f);
          hsm[(rf*16 + quad*4 + i)*264 + col] = f2bf(h);
        }
    }
    __syncthreads();                 // BAR2: hsm ready

    // ---- layer 2: uh_e colfrag = wave; logit via broadcast Wa2 row ----
    f32x4 acc2[4];
    f32x4 accl = {0.f, 0.f, 0.f, 0.f};
    #pragma unroll
    for (int rf = 0; rf < 4; rf++) acc2[rf] = {0.f, 0.f, 0.f, 0.f};
    #pragma unroll
    for (int k = 0; k < 4; k++) {
      #pragma unroll
      for (int rf = 0; rf < 4; rf++) {
        bf16x8 ae = *(const bf16x8*)&hsm[(rf*16 + r)*264 + k*32 + quad*8];
        acc2[rf] = __builtin_amdgcn_mfma_f32_16x16x32_bf16(ae, wv2[k], acc2[rf], 0, 0, 0);
      }
      bf16x8 al = *(const bf16x8*)&hsm[(wave*16 + r)*264 + 128 + k*32 + quad*8];
      accl = __builtin_amdgcn_mfma_f32_16x16x32_bf16(al, wvl[k], accl, 0, 0, 0);
    }
    __syncthreads();                 // BAR3: hsm reads done (hsm dead)

    // write next-tile eins into the (dead) hsm region
    if (tt + 1 < ntiles) {
      #pragma unroll
      for (int i = 0; i < 4; i++) {
        int idx = i*256 + t, e = idx >> 4, c = idx & 15;
        *(uint2*)&eins[e*168 + c*4]      = gs[i];
        *(uint2*)&eins[e*168 + 64 + c*4] = gd[i];
      }
      #pragma unroll
      for (int i = 0; i < 2; i++) {
        int idx = i*256 + t, e = idx >> 3, c = idx & 7;
        *(uint2*)&eins[e*168 + 128 + c*4] = f4tobf(gef[i]);
      }
    }

    // epilogue: outs (separate buffer); exp(logit) -> global
    {
      int col = wave*16 + r;
      #pragma unroll
      for (int rf = 0; rf < 4; rf++)
        #pragma unroll
        for (int i = 0; i < 4; i++)
          outs[(rf*16 + quad*4 + i)*64 + col] = acc2[rf][i] + bias2;
    }
    if (r == 0) {
      #pragma unroll
      for (int i = 0; i < 4; i++) {
        int row = wave*16 + quad*4 + i;
        float x = __expf(fminf(fmaxf(accl[i] + biasl, -50.f), 50.f));
        exu[nbase + row] = x;
      }
    }
    __syncthreads();                 // BAR4: outs + eins(t+1) ready

    // coalesced uh_e store (outs reads complete before next BAR1)
    #pragma unroll
    for (int i = 0; i < 4; i++) {
      int idx = i*256 + t, row = idx >> 4, c = idx & 15;
      *(float4*)(uh_e + (size_t)(nbase + row)*64 + c*4) = *(const float4*)&outs[row*64 + c*4];
    }
  }
}

// ---------------- attention-weighted aggregation (wave per node, linked list) ---------
__global__ void agg_kernel(const int* __restrict__ head, const int* __restrict__ nxt,
                           const float* __restrict__ exu,
                           const float* __restrict__ uh_e, float* __restrict__ aggf)
{
  int gid = blockIdx.x * 256 + threadIdx.x;
  int v = gid >> 6, lane = gid & 63;
  if (v >= NN) return;
  float acc = 0.f, s = 0.f;
  int e = head[v];
  while (e >= 0) {
    float x = exu[e];                // broadcast load
    s += x;
    acc += x * uh_e[(size_t)e*64 + lane];
    e = nxt[e];
  }
  aggf[(size_t)v*64 + lane] = acc / fmaxf(s, 1e-38f);
}

// ---------------- node MLP (MFMA); reads agg from uh_n region, overwrites with uh_n ----
__global__ __launch_bounds__(256, 4) void node_kernel(
    const float* __restrict__ aggf, const float* __restrict__ nf,
    const u16* __restrict__ wn1t, const u16* __restrict__ wn2t,
    const float* __restrict__ bn1, const float* __restrict__ bn2,
    float* __restrict__ uh_n)
{
  __shared__ u16 smem2[8704];        // 17408 B union
  u16* xs = smem2;                   // [64][136]
  float* outs = (float*)smem2;       // [64][64]

  const int t = threadIdx.x;
  const int base = blockIdx.x * 64;

  #pragma unroll
  for (int i = 0; i < 8; i++) {
    int idx = i*256 + t;
    int row = idx >> 5, c = idx & 31;
    int v = base + row;
    float4 f = {0.f, 0.f, 0.f, 0.f};
    if (v < NN) {
      if (c < 16) f = *(const float4*)(aggf + (size_t)v*64 + c*4);
      else        f = *(const float4*)(nf   + (size_t)v*64 + (c-16)*4);
    }
    *(uint2*)&xs[row*136 + c*4] = f4tobf(f);
  }
  __syncthreads();

  const int lane = t & 63, wave = t >> 6;
  const int r = lane & 15, quad = lane >> 4;

  f32x4 acc1[8];
  #pragma unroll
  for (int i = 0; i < 8; i++) acc1[i] = {0.f, 0.f, 0.f, 0.f};
  #pragma unroll
  for (int k0 = 0; k0 < 128; k0 += 32) {
    bf16x8 a = *(const bf16x8*)&xs[(wave*16 + r)*136 + k0 + quad*8];
    #pragma unroll
    for (int tt = 0; tt < 8; tt++) {
      bf16x8 b = *(const bf16x8*)(wn1t + (size_t)(tt*16 + r)*128 + k0 + quad*8);
      acc1[tt] = __builtin_amdgcn_mfma_f32_16x16x32_bf16(a, b, acc1[tt], 0, 0, 0);
    }
  }
  __syncthreads();

  u16* hb = smem2 + wave*(16*136);
  #pragma unroll
  for (int tt = 0; tt < 8; tt++) {
    int col = tt*16 + r;
    float bias = bn1[col];
    #pragma unroll
    for (int i = 0; i < 4; i++) {
      float h = fmaxf(acc1[tt][i] + bias, 0.f);
      hb[(quad*4 + i)*136 + col] = f2bf(h);
    }
  }
  __syncthreads();

  f32x4 acc2[4];
  #pragma unroll
  for (int i = 0; i < 4; i++) acc2[i] = {0.f, 0.f, 0.f, 0.f};
  #pragma unroll
  for (int k0 = 0; k0 < 128; k0 += 32) {
    bf16x8 a = *(const bf16x8*)&hb[r*136 + k0 + quad*8];
    #pragma unroll
    for (int tt = 0; tt < 4; tt++) {
      bf16x8 b = *(const bf16x8*)(wn2t + (size_t)(tt*16 + r)*128 + k0 + quad*8);
      acc2[tt] = __builtin_amdgcn_mfma_f32_16x16x32_bf16(a, b, acc2[tt], 0, 0, 0);
    }
  }
  __syncthreads();

  #pragma unroll
  for (int tt = 0; tt < 4; tt++) {
    int col = tt*16 + r;
    float bias = bn2[col];
    #pragma unroll
    for (int i = 0; i < 4; i++)
      outs[(wave*16 + quad*4 + i)*64 + col] = acc2[tt][i] + bias;
  }
  __syncthreads();

  #pragma unroll
  for (int i = 0; i < 4; i++) {
    int idx = i*256 + t;
    int row = idx >> 4, c = idx & 15;
    int v2 = base + row;
    if (v2 < NN)
      *(float4*)(uh_n + (size_t)v2*64 + c*4) = *(const float4*)&outs[row*64 + c*4];
  }
}

// ---------------- launch ----------------
extern "C" void kernel_launch(void* const* d_in, const int* in_sizes, int n_in,
                              void* d_out, int out_size, void* d_ws, size_t ws_size,
                              hipStream_t stream)
{
  const float* nf  = (const float*)d_in[0];
  const float* ef  = (const float*)d_in[1];
  const int*   src = (const int*)d_in[2];
  const int*   dst = (const int*)d_in[3];
  const float* We1 = (const float*)d_in[4];
  const float* be1 = (const float*)d_in[5];
  const float* We2 = (const float*)d_in[6];
  const float* be2 = (const float*)d_in[7];
  const float* Wa1 = (const float*)d_in[8];
  const float* ba1 = (const float*)d_in[9];
  const float* Wa2 = (const float*)d_in[10];
  const float* ba2 = (const float*)d_in[11];
  const float* Wn1 = (const float*)d_in[12];
  const float* bn1 = (const float*)d_in[13];
  const float* Wn2 = (const float*)d_in[14];
  const float* bn2 = (const float*)d_in[15];

  // workspace layout (bytes), total 6,951,552 B (~6.6 MiB)
  char* ws = (char*)d_ws;
  u16*   w1t    = (u16*)  (ws + 0);         //  81920
  u16*   w2t    = (u16*)  (ws + 81920);     //  20480
  u16*   wn1t   = (u16*)  (ws + 102400);    //  32768
  u16*   wn2t   = (u16*)  (ws + 135168);    //  16384
  float* exu    = (float*)(ws + 151552);    //  NE*4
  int*   head   = (int*)  (ws + 3551552);   //  NN*4
  int*   nxt    = (int*)  (ws + 3751552);   //  NE*4 -> end 6,951,552

  float* uh_n = (float*)d_out;                     // [NN, 64] f32
  float* uh_e = (float*)d_out + (size_t)NN * 64;   // [NE, 64] f32
  // nfb (bf16 nf, 6.4 MB) lives in uh_n region: consumed only by edge_kernel,
  // overwritten afterwards by agg_kernel's aggf output.
  u16*   nfb  = (u16*)d_out;
  float* aggf = uh_n;

  prep_kernel<<<492, 256, 0, stream>>>(We1, Wa1, We2, Wa2, Wn1, Wn2,
                                       w1t, w2t, wn1t, wn2t, head);
  nfbf_kernel<<<3125, 256, 0, stream>>>(nf, nfb);
  link_kernel<<<(NE + 255)/256, 256, 0, stream>>>(dst, head, nxt);
  edge_kernel<<<EGRID, 256, 0, stream>>>(nfb, ef, src, dst, w1t, w2t,
                                         be1, ba1, be2, ba2, uh_e, exu);
  agg_kernel<<<(NN*64)/256, 256, 0, stream>>>(head, nxt, exu, uh_e, aggf);
  node_kernel<<<(NN + 63)/64, 256, 0, stream>>>(aggf, nf, wn1t, wn2t, bn1, bn2, uh_n);
}